// Round 8
// baseline (315.744 us; speedup 1.0000x reference)
//
#include <hip/hip_runtime.h>
#include <cstdint>

typedef __bf16 bf16;
typedef __attribute__((ext_vector_type(8))) __bf16 bf16x8;
typedef __attribute__((ext_vector_type(4))) __bf16 bf16x4;
typedef __attribute__((ext_vector_type(4))) float f32x4;
typedef __attribute__((ext_vector_type(4))) short short4_t;

__device__ __forceinline__ void load_lds16(const void* g, void* l) {
  __builtin_amdgcn_global_load_lds(
      (const __attribute__((address_space(1))) unsigned int*)g,
      (__attribute__((address_space(3))) unsigned int*)l, 16, 0, 0);
}

__device__ __forceinline__ float fast_exp2(float x) {
  float r;
  asm volatile("v_exp_f32 %0, %1" : "=v"(r) : "v"(x));
  return r;
}

// ---------------------------------------------------------------------------
// GEMM: C[M,N] = A[M,K] @ Bt[N,K]^T (+bias). 128x128 tile, BK=64, 256 thr.
// VSPLIT: blocks with bn >= 2560 (the V columns of QKV) write the TRANSPOSED
// result directly to Vt[(b*4+g)*128 + d][t] instead of C — the V region of
// qkv is never read, and the separate transpose_v kernel disappears.
// (R8-verified config: 297.7 µs total.)
// ---------------------------------------------------------------------------
template <bool OUT_F32, bool VSPLIT>
__global__ __launch_bounds__(256) void gemm_bt(
    const bf16* __restrict__ A, const bf16* __restrict__ Bt,
    const float* __restrict__ bias, void* __restrict__ Cv,
    int M, int N, int K, bf16* __restrict__ Vt) {
  // sA/sB live in smem; V-blocks reuse it post-loop as a 128x136 transpose tile.
  __shared__ __align__(16) bf16 smem[VSPLIT ? 128 * 136 : 128 * 128];
  bf16* sA = smem;
  bf16* sB = smem + 128 * 64;
  const int t = threadIdx.x;
  const int w = t >> 6, lane = t & 63;
  const int quad = lane >> 4, l16 = lane & 15;
  const int wm = (w >> 1) * 64, wn = (w & 1) * 64;
  const int bm = blockIdx.y * 128, bn = blockIdx.x * 128;

  f32x4 acc[4][4] = {};
  const int srow = lane >> 3;
  const int sg = lane & 7;

  for (int kt = 0; kt < (K >> 6); ++kt) {
    const int k0 = kt << 6;
#pragma unroll
    for (int c2 = 0; c2 < 4; ++c2) {
      int c = c2 * 4 + w;
      int row = c * 8 + srow;
      int gg = sg ^ (row & 7);
      load_lds16(A + (int64_t)(bm + row) * K + k0 + gg * 8, sA + c * 512);
      load_lds16(Bt + (int64_t)(bn + row) * K + k0 + gg * 8, sB + c * 512);
    }
    asm volatile("s_waitcnt vmcnt(0)" ::: "memory");
    __syncthreads();
#pragma unroll
    for (int ks = 0; ks < 2; ++ks) {
      bf16x8 af[4], bfr[4];
#pragma unroll
      for (int i = 0; i < 4; ++i) {
        int m = wm + i * 16 + l16;
        af[i] = *(const bf16x8*)(sA + m * 64 + (((ks * 4 + quad) ^ (l16 & 7)) * 8));
        int n = wn + i * 16 + l16;
        bfr[i] = *(const bf16x8*)(sB + n * 64 + (((ks * 4 + quad) ^ (l16 & 7)) * 8));
      }
#pragma unroll
      for (int i = 0; i < 4; ++i)
#pragma unroll
        for (int j = 0; j < 4; ++j)
          acc[i][j] = __builtin_amdgcn_mfma_f32_16x16x32_bf16(af[i], bfr[j],
                                                              acc[i][j], 0, 0, 0);
    }
    __syncthreads();
  }

  if (VSPLIT && bn >= 2560) {
    // ---- V-block epilogue: bias-add, LDS transpose, coalesced Vt write ----
#pragma unroll
    for (int i = 0; i < 4; ++i) {
      int m0 = wm + i * 16 + quad * 4;
#pragma unroll
      for (int j = 0; j < 4; ++j) {
        int n_l = wn + j * 16 + l16;
        float bvv = bias ? bias[bn + n_l] : 0.0f;
        bf16x4 o4;
#pragma unroll
        for (int r = 0; r < 4; ++r) o4[r] = (bf16)(acc[i][j][r] + bvv);
        *(bf16x4*)(smem + n_l * 136 + m0) = o4;
      }
    }
    __syncthreads();
    const int n_l = t >> 1, half = t & 1;
    const int g = (bn - 2560) >> 7;
    const int b2 = bm >> 11;
    const int t0 = (bm & 2047) + half * 64;
    bf16* dst = Vt + ((int64_t)((b2 * 4 + g) * 128 + n_l)) * 2048 + t0;
    const bf16* src = smem + n_l * 136 + half * 64;
#pragma unroll
    for (int c = 0; c < 8; ++c)
      *(bf16x8*)(dst + c * 8) = *(const bf16x8*)(src + c * 8);
    return;
  }

#pragma unroll
  for (int i = 0; i < 4; ++i) {
    int gm = bm + wm + i * 16 + quad * 4;
#pragma unroll
    for (int j = 0; j < 4; ++j) {
      int gn = bn + wn + j * 16 + l16;
      float bvv = bias ? bias[gn] : 0.0f;
#pragma unroll
      for (int r = 0; r < 4; ++r) {
        float v = acc[i][j][r] + bvv;
        if (OUT_F32)
          ((float*)Cv)[(int64_t)(gm + r) * N + gn] = v;
        else
          ((bf16*)Cv)[(int64_t)(gm + r) * N + gn] = (bf16)v;
      }
    }
  }
}

// ---------------------------------------------------------------------------
// Flash attention (causal GQA) — R5 version (best measured: 83.5 µs, 4 runs).
// Mirror-paired q-tiles (A=p, B=31-p), KVBLK=64, P in regs via 16x16x16 PV.
// trip-balance: p = x for b=0, 15-x for b=1 (co-resident trips sum 49).
// CC pre-folded into Q regs; T13 defer-rescale; T5 setprio around MFMA.
// R11 tweak: stage issues all K loads before V loads (same dests/waits;
// biases completion order toward K, which QK consumes first).
// ---------------------------------------------------------------------------
__global__ __launch_bounds__(256, 2) void attn(
    const bf16* __restrict__ QKV, const bf16* __restrict__ Vt,
    bf16* __restrict__ Out) {
  constexpr float CC = 0.08838834764831845f * 1.44269504088896f;  // scale*log2e
  __shared__ __align__(16) bf16 sK[2][64 * 128];
  __shared__ __align__(16) bf16 sV[2][128 * 64];

  const int t = threadIdx.x;
  const int w = t >> 6, lane = t & 63;
  const int quad = lane >> 4, l16 = lane & 15;
  const int h = blockIdx.y, b = blockIdx.z;
  const int p = (b == 0) ? (int)blockIdx.x : 15 - (int)blockIdx.x;
  const int g = h >> 2;
  const int wr0 = w * 16;
  const int kbase = 2048 + g * 128;
  const bf16* vtb = Vt + (int64_t)((b * 4 + g) * 128) * 2048;
  const int rk = lane >> 4, rv = lane >> 3, sgv = lane & 7;
  const int qrow0A = p * 64, qrow0B = (31 - p) * 64;
  const int niters = 32 - p;

  auto stage = [&](int n0, bf16* sKb, bf16* sVb) {
#pragma unroll
    for (int c2 = 0; c2 < 4; ++c2) {
      int c = c2 * 4 + w;
      int rowk = c * 4 + rk;
      int ggk = (l16 & 8) | ((l16 ^ rowk) & 7);
      load_lds16(QKV + (int64_t)(b * 2048 + n0 + rowk) * 3072 + kbase + ggk * 8,
                 sKb + c * 512);
    }
#pragma unroll
    for (int c2 = 0; c2 < 4; ++c2) {
      int c = c2 * 4 + w;
      int rowv = c * 8 + rv;
      int ggv = sgv ^ (rowv & 7);
      load_lds16(vtb + (int64_t)rowv * 2048 + n0 + ggv * 8, sVb + c * 512);
    }
  };

  stage(0, sK[0], sV[0]);

  // Q fragments, pre-scaled by CC.
  bf16x8 qreg[2][4];
#pragma unroll
  for (int u = 0; u < 2; ++u) {
    int qr = (u == 0 ? qrow0A : qrow0B);
#pragma unroll
    for (int ks = 0; ks < 4; ++ks) {
      bf16x8 v = *(const bf16x8*)(QKV +
          (int64_t)(b * 2048 + qr + wr0 + l16) * 3072 + h * 128 + ks * 32 +
          quad * 8);
#pragma unroll
      for (int e = 0; e < 8; ++e) v[e] = (bf16)((float)v[e] * CC);
      qreg[u][ks] = v;
    }
  }

  f32x4 oacc[2][8] = {};
  float mrow[2] = {-3.0e38f, -3.0e38f};
  float lrow[2] = {0.f, 0.f};

  for (int it = 0; it < niters; ++it) {
    const int cur = it & 1;
    const int n0 = it * 64;
    bf16* sKc = sK[cur];
    bf16* sVc = sV[cur];
    const bool actA = (it <= p);

    asm volatile("s_waitcnt vmcnt(0)\n\ts_barrier" ::: "memory");
    if (it + 1 < niters) stage(n0 + 64, sK[cur ^ 1], sV[cur ^ 1]);

    // ---- S^T = K Q^T : sacc[u][mj], row=kv=mj*16+quad*4+r, col=q=l16 ----
    f32x4 sacc[2][4] = {};
    if (actA) {
#pragma unroll
      for (int ks = 0; ks < 4; ++ks) {
        bf16x8 ak[4];
#pragma unroll
        for (int mj = 0; mj < 4; ++mj) {
          int kvr = mj * 16 + l16;
          int G = ks * 4 + quad;
          int slot = (G & 8) | ((G ^ kvr) & 7);
          ak[mj] = *(const bf16x8*)(sKc + kvr * 128 + slot * 8);
        }
        __builtin_amdgcn_s_setprio(1);
#pragma unroll
        for (int mj = 0; mj < 4; ++mj) {
          sacc[0][mj] = __builtin_amdgcn_mfma_f32_16x16x32_bf16(
              ak[mj], qreg[0][ks], sacc[0][mj], 0, 0, 0);
          sacc[1][mj] = __builtin_amdgcn_mfma_f32_16x16x32_bf16(
              ak[mj], qreg[1][ks], sacc[1][mj], 0, 0, 0);
        }
        __builtin_amdgcn_s_setprio(0);
      }
    } else {
#pragma unroll
      for (int ks = 0; ks < 4; ++ks) {
        bf16x8 ak[4];
#pragma unroll
        for (int mj = 0; mj < 4; ++mj) {
          int kvr = mj * 16 + l16;
          int G = ks * 4 + quad;
          int slot = (G & 8) | ((G ^ kvr) & 7);
          ak[mj] = *(const bf16x8*)(sKc + kvr * 128 + slot * 8);
        }
        __builtin_amdgcn_s_setprio(1);
#pragma unroll
        for (int mj = 0; mj < 4; ++mj)
          sacc[1][mj] = __builtin_amdgcn_mfma_f32_16x16x32_bf16(
              ak[mj], qreg[1][ks], sacc[1][mj], 0, 0, 0);
        __builtin_amdgcn_s_setprio(0);
      }
    }

    // ---- online softmax (log2 domain; CC already folded) -> pb in regs ----
    short4_t pb[2][4];
    auto softmax_u = [&](int u, bool last, int qrow0u) {
      if (last) {
        int qg = qrow0u + wr0 + l16;
#pragma unroll
        for (int mj = 0; mj < 4; ++mj)
#pragma unroll
          for (int r = 0; r < 4; ++r) {
            int kv = n0 + mj * 16 + quad * 4 + r;
            if (kv > qg) sacc[u][mj][r] = -3.0e38f;
          }
      }
      f32x4 m01, m23;
#pragma unroll
      for (int r = 0; r < 4; ++r) {
        m01[r] = fmaxf(sacc[u][0][r], sacc[u][1][r]);
        m23[r] = fmaxf(sacc[u][2][r], sacc[u][3][r]);
      }
      float mx = fmaxf(fmaxf(fmaxf(m01[0], m01[1]), fmaxf(m01[2], m01[3])),
                       fmaxf(fmaxf(m23[0], m23[1]), fmaxf(m23[2], m23[3])));
      mx = fmaxf(mx, __shfl_xor(mx, 16));
      mx = fmaxf(mx, __shfl_xor(mx, 32));
      if (!__all(mx <= mrow[u] + 11.0f)) {  // T13 defer-rescale
        float mnew = fmaxf(mrow[u], mx);
        float alpha = fast_exp2(mrow[u] - mnew);
        lrow[u] *= alpha;
#pragma unroll
        for (int dj = 0; dj < 8; ++dj)
#pragma unroll
          for (int r = 0; r < 4; ++r) oacc[u][dj][r] *= alpha;
        mrow[u] = mnew;
      }
      float rs = 0.f;
#pragma unroll
      for (int mj = 0; mj < 4; ++mj) {
        bf16x4 p4;
#pragma unroll
        for (int r = 0; r < 4; ++r) {
          float pv = fast_exp2(sacc[u][mj][r] - mrow[u]);
          rs += pv;
          p4[r] = (bf16)pv;
        }
        pb[u][mj] = __builtin_bit_cast(short4_t, p4);
      }
      rs += __shfl_xor(rs, 16);
      rs += __shfl_xor(rs, 32);
      lrow[u] += rs;
    };
    if (actA) softmax_u(0, it == p, qrow0A);
    softmax_u(1, it == niters - 1, qrow0B);

    // ---- O^T += V^T P^T via 16x16x16 (P in registers, no sP) ----
#pragma unroll
    for (int mj = 0; mj < 4; ++mj) {
      const int sbase = mj * 2 + (quad >> 1);
      const int soff = (quad & 1) * 4;
      short4_t av[8];
#pragma unroll
      for (int dj = 0; dj < 8; ++dj) {
        int d = dj * 16 + l16;
        av[dj] = *(const short4_t*)(sVc + d * 64 + ((sbase ^ (d & 7)) * 8) + soff);
      }
      __builtin_amdgcn_s_setprio(1);
      if (actA) {
#pragma unroll
        for (int dj = 0; dj < 8; ++dj) {
          oacc[0][dj] = __builtin_amdgcn_mfma_f32_16x16x16bf16_1k(
              av[dj], pb[0][mj], oacc[0][dj], 0, 0, 0);
          oacc[1][dj] = __builtin_amdgcn_mfma_f32_16x16x16bf16_1k(
              av[dj], pb[1][mj], oacc[1][dj], 0, 0, 0);
        }
      } else {
#pragma unroll
        for (int dj = 0; dj < 8; ++dj)
          oacc[1][dj] = __builtin_amdgcn_mfma_f32_16x16x16bf16_1k(
              av[dj], pb[1][mj], oacc[1][dj], 0, 0, 0);
      }
      __builtin_amdgcn_s_setprio(0);
    }
  }

  // ---- epilogue ----
#pragma unroll
  for (int u = 0; u < 2; ++u) {
    int qrow0u = (u == 0 ? qrow0A : qrow0B);
    float inv = 1.0f / lrow[u];
    int64_t grow = b * 2048 + qrow0u + wr0 + l16;
#pragma unroll
    for (int dj = 0; dj < 8; ++dj) {
      bf16x4 o4;
#pragma unroll
      for (int r = 0; r < 4; ++r) o4[r] = (bf16)(oacc[u][dj][r] * inv);
      *(bf16x4*)(Out + grow * 2048 + h * 128 + dj * 16 + quad * 4) = o4;
    }
  }
}

// ---------------------------------------------------------------------------
// Fused prep: convert_x (blocks 0..8191), transpose Wq/Wk/Wv/Wo (64x64 tiles),
// concat bias (last 12 blocks). One launch instead of six.
// ---------------------------------------------------------------------------
__device__ __forceinline__ void tr_tile(const float* __restrict__ W,
                                        bf16* __restrict__ Wt, int K, int N,
                                        int bx, int by, int t, float* tile) {
  int tx = t & 63, ty = t >> 6;
#pragma unroll
  for (int q2 = 0; q2 < 16; ++q2) {
    int r = ty + q2 * 4;
    tile[r * 65 + tx] = W[(int64_t)(by * 64 + r) * N + bx * 64 + tx];
  }
  __syncthreads();
#pragma unroll
  for (int q2 = 0; q2 < 16; ++q2) {
    int n = ty + q2 * 4;
    Wt[(int64_t)(bx * 64 + n) * K + by * 64 + tx] = (bf16)tile[tx * 65 + n];
  }
}

__global__ __launch_bounds__(256) void prep(
    const float* __restrict__ x, const float* __restrict__ Wq,
    const float* __restrict__ Wk, const float* __restrict__ Wv,
    const float* __restrict__ Wo, const float* __restrict__ bq,
    const float* __restrict__ bk, const float* __restrict__ bv,
    bf16* __restrict__ xb, bf16* __restrict__ wqkvT, bf16* __restrict__ woT,
    float* __restrict__ bqkv) {
  __shared__ float tile[64 * 65];
  const int bid = blockIdx.x;
  const int t = threadIdx.x;
  if (bid < 8192) {  // convert x -> bf16
    int idx = bid * 256 + t;
    float4 v = ((const float4*)x)[idx];
    bf16x4 o = {(bf16)v.x, (bf16)v.y, (bf16)v.z, (bf16)v.w};
    ((bf16x4*)xb)[idx] = o;
  } else if (bid < 8192 + 1024) {  // Wq
    int b2 = bid - 8192;
    tr_tile(Wq, wqkvT, 2048, 2048, b2 & 31, b2 >> 5, t, tile);
  } else if (bid < 8192 + 1024 + 256) {  // Wk
    int b2 = bid - (8192 + 1024);
    tr_tile(Wk, wqkvT + 2048 * 2048, 2048, 512, b2 & 7, b2 >> 3, t, tile);
  } else if (bid < 8192 + 1024 + 512) {  // Wv
    int b2 = bid - (8192 + 1024 + 256);
    tr_tile(Wv, wqkvT + 2560 * 2048, 2048, 512, b2 & 7, b2 >> 3, t, tile);
  } else if (bid < 8192 + 1024 + 512 + 1024) {  // Wo
    int b2 = bid - (8192 + 1024 + 512);
    tr_tile(Wo, woT, 2048, 2048, b2 & 31, b2 >> 5, t, tile);
  } else {  // bias concat (12 blocks)
    int i = (bid - (8192 + 1024 + 512 + 1024)) * 256 + t;
    if (i < 3072)
      bqkv[i] = i < 2048 ? bq[i] : (i < 2560 ? bk[i - 2048] : bv[i - 2560]);
  }
}

// ---------------------------------------------------------------------------
extern "C" void kernel_launch(void* const* d_in, const int* in_sizes, int n_in,
                              void* d_out, int out_size, void* d_ws,
                              size_t ws_size, hipStream_t stream) {
  const float* x = (const float*)d_in[0];
  const float* Wq = (const float*)d_in[1];
  const float* bq = (const float*)d_in[2];
  const float* Wk = (const float*)d_in[3];
  const float* bk = (const float*)d_in[4];
  const float* Wv = (const float*)d_in[5];
  const float* bv = (const float*)d_in[6];
  const float* Wo = (const float*)d_in[7];
  const float* bo = (const float*)d_in[8];
  float* out = (float*)d_out;

  char* ws = (char*)d_ws;
  bf16* xb = (bf16*)(ws);
  bf16* wqkvT = (bf16*)(ws + 16777216);
  bf16* woT = (bf16*)(ws + 29360128);
  float* bqkv = (float*)(ws + 37748736);
  bf16* qkv = (bf16*)(ws + 37761024);
  bf16* vt = (bf16*)(ws + 62926848);
  bf16* attnb = (bf16*)(ws + 67121152);

  prep<<<8192 + 1024 + 512 + 1024 + 12, 256, 0, stream>>>(
      x, Wq, Wk, Wv, Wo, bq, bk, bv, xb, wqkvT, woT, bqkv);

  // QKV = xb @ WqkvT^T + bqkv [4096 x 3072]; V columns go transposed to vt.
  gemm_bt<false, true><<<dim3(24, 32), 256, 0, stream>>>(
      xb, wqkvT, bqkv, qkv, 4096, 3072, 2048, vt);
  attn<<<dim3(16, 16, 2), 256, 0, stream>>>(qkv, vt, attnb);
  // out = attnb @ WoT^T + bo    [4096 x 2048] fp32
  gemm_bt<true, false><<<dim3(16, 32), 256, 0, stream>>>(
      attnb, woT, bo, out, 4096, 2048, 2048, nullptr);
}

// Round 9
// 292.566 us; speedup vs baseline: 1.0792x; 1.0792x over previous
//
#include <hip/hip_runtime.h>
#include <cstdint>

typedef __bf16 bf16;
typedef __attribute__((ext_vector_type(8))) __bf16 bf16x8;
typedef __attribute__((ext_vector_type(4))) __bf16 bf16x4;
typedef __attribute__((ext_vector_type(4))) float f32x4;
typedef __attribute__((ext_vector_type(4))) short short4_t;

__device__ __forceinline__ void load_lds16(const void* g, void* l) {
  __builtin_amdgcn_global_load_lds(
      (const __attribute__((address_space(1))) unsigned int*)g,
      (__attribute__((address_space(3))) unsigned int*)l, 16, 0, 0);
}

__device__ __forceinline__ float fast_exp2(float x) {
  float r;
  asm volatile("v_exp_f32 %0, %1" : "=v"(r) : "v"(x));
  return r;
}

// ---------------------------------------------------------------------------
// GEMM: C[M,N] = A[M,K] @ Bt[N,K]^T (+bias). 128x128 tile, BK=64, 256 thr.
// __launch_bounds__(256,4): pin VGPR <= 128 -> 4 blocks/CU (was ~3). The m97
// structure's throughput comes from cross-block overlap of the per-tile
// barrier drain (m114); +1 resident block = +33% overlap capacity. LDS
// (32 KiB) permits 5 blocks/CU, so VGPR is the binding limit.
// VSPLIT: blocks with bn >= 2560 (the V columns of QKV) write the TRANSPOSED
// result directly to Vt[(b*4+g)*128 + d][t]; the V region of qkv is never
// read and the separate transpose_v kernel disappears. (R8-verified.)
// ---------------------------------------------------------------------------
template <bool OUT_F32, bool VSPLIT>
__global__ __launch_bounds__(256, 4) void gemm_bt(
    const bf16* __restrict__ A, const bf16* __restrict__ Bt,
    const float* __restrict__ bias, void* __restrict__ Cv,
    int M, int N, int K, bf16* __restrict__ Vt) {
  // sA/sB live in smem; V-blocks reuse it post-loop as a 128x136 transpose tile.
  __shared__ __align__(16) bf16 smem[VSPLIT ? 128 * 136 : 128 * 128];
  bf16* sA = smem;
  bf16* sB = smem + 128 * 64;
  const int t = threadIdx.x;
  const int w = t >> 6, lane = t & 63;
  const int quad = lane >> 4, l16 = lane & 15;
  const int wm = (w >> 1) * 64, wn = (w & 1) * 64;
  const int bm = blockIdx.y * 128, bn = blockIdx.x * 128;

  f32x4 acc[4][4] = {};
  const int srow = lane >> 3;
  const int sg = lane & 7;

  for (int kt = 0; kt < (K >> 6); ++kt) {
    const int k0 = kt << 6;
#pragma unroll
    for (int c2 = 0; c2 < 4; ++c2) {
      int c = c2 * 4 + w;
      int row = c * 8 + srow;
      int gg = sg ^ (row & 7);
      load_lds16(A + (int64_t)(bm + row) * K + k0 + gg * 8, sA + c * 512);
      load_lds16(Bt + (int64_t)(bn + row) * K + k0 + gg * 8, sB + c * 512);
    }
    asm volatile("s_waitcnt vmcnt(0)" ::: "memory");
    __syncthreads();
#pragma unroll
    for (int ks = 0; ks < 2; ++ks) {
      bf16x8 af[4], bfr[4];
#pragma unroll
      for (int i = 0; i < 4; ++i) {
        int m = wm + i * 16 + l16;
        af[i] = *(const bf16x8*)(sA + m * 64 + (((ks * 4 + quad) ^ (l16 & 7)) * 8));
        int n = wn + i * 16 + l16;
        bfr[i] = *(const bf16x8*)(sB + n * 64 + (((ks * 4 + quad) ^ (l16 & 7)) * 8));
      }
#pragma unroll
      for (int i = 0; i < 4; ++i)
#pragma unroll
        for (int j = 0; j < 4; ++j)
          acc[i][j] = __builtin_amdgcn_mfma_f32_16x16x32_bf16(af[i], bfr[j],
                                                              acc[i][j], 0, 0, 0);
    }
    __syncthreads();
  }

  if (VSPLIT && bn >= 2560) {
    // ---- V-block epilogue: bias-add, LDS transpose, coalesced Vt write ----
#pragma unroll
    for (int i = 0; i < 4; ++i) {
      int m0 = wm + i * 16 + quad * 4;
#pragma unroll
      for (int j = 0; j < 4; ++j) {
        int n_l = wn + j * 16 + l16;
        float bvv = bias ? bias[bn + n_l] : 0.0f;
        bf16x4 o4;
#pragma unroll
        for (int r = 0; r < 4; ++r) o4[r] = (bf16)(acc[i][j][r] + bvv);
        *(bf16x4*)(smem + n_l * 136 + m0) = o4;
      }
    }
    __syncthreads();
    const int n_l = t >> 1, half = t & 1;
    const int g = (bn - 2560) >> 7;
    const int b2 = bm >> 11;
    const int t0 = (bm & 2047) + half * 64;
    bf16* dst = Vt + ((int64_t)((b2 * 4 + g) * 128 + n_l)) * 2048 + t0;
    const bf16* src = smem + n_l * 136 + half * 64;
#pragma unroll
    for (int c = 0; c < 8; ++c)
      *(bf16x8*)(dst + c * 8) = *(const bf16x8*)(src + c * 8);
    return;
  }

#pragma unroll
  for (int i = 0; i < 4; ++i) {
    int gm = bm + wm + i * 16 + quad * 4;
#pragma unroll
    for (int j = 0; j < 4; ++j) {
      int gn = bn + wn + j * 16 + l16;
      float bvv = bias ? bias[gn] : 0.0f;
#pragma unroll
      for (int r = 0; r < 4; ++r) {
        float v = acc[i][j][r] + bvv;
        if (OUT_F32)
          ((float*)Cv)[(int64_t)(gm + r) * N + gn] = v;
        else
          ((bf16*)Cv)[(int64_t)(gm + r) * N + gn] = (bf16)v;
      }
    }
  }
}

// ---------------------------------------------------------------------------
// Flash attention (causal GQA) — R5 version (83.0-84.0 µs over 5 runs).
// Mirror-paired q-tiles (A=p, B=31-p), KVBLK=64, P in regs via 16x16x16 PV.
// trip-balance: p = x for b=0, 15-x for b=1 (co-resident trips sum 49).
// CC pre-folded into Q regs; T13 defer-rescale; T5 setprio around MFMA.
// ---------------------------------------------------------------------------
__global__ __launch_bounds__(256, 2) void attn(
    const bf16* __restrict__ QKV, const bf16* __restrict__ Vt,
    bf16* __restrict__ Out) {
  constexpr float CC = 0.08838834764831845f * 1.44269504088896f;  // scale*log2e
  __shared__ __align__(16) bf16 sK[2][64 * 128];
  __shared__ __align__(16) bf16 sV[2][128 * 64];

  const int t = threadIdx.x;
  const int w = t >> 6, lane = t & 63;
  const int quad = lane >> 4, l16 = lane & 15;
  const int h = blockIdx.y, b = blockIdx.z;
  const int p = (b == 0) ? (int)blockIdx.x : 15 - (int)blockIdx.x;
  const int g = h >> 2;
  const int wr0 = w * 16;
  const int kbase = 2048 + g * 128;
  const bf16* vtb = Vt + (int64_t)((b * 4 + g) * 128) * 2048;
  const int rk = lane >> 4, rv = lane >> 3, sgv = lane & 7;
  const int qrow0A = p * 64, qrow0B = (31 - p) * 64;
  const int niters = 32 - p;

  auto stage = [&](int n0, bf16* sKb, bf16* sVb) {
#pragma unroll
    for (int c2 = 0; c2 < 4; ++c2) {
      int c = c2 * 4 + w;
      int rowk = c * 4 + rk;
      int ggk = (l16 & 8) | ((l16 ^ rowk) & 7);
      load_lds16(QKV + (int64_t)(b * 2048 + n0 + rowk) * 3072 + kbase + ggk * 8,
                 sKb + c * 512);
      int rowv = c * 8 + rv;
      int ggv = sgv ^ (rowv & 7);
      load_lds16(vtb + (int64_t)rowv * 2048 + n0 + ggv * 8, sVb + c * 512);
    }
  };

  stage(0, sK[0], sV[0]);

  // Q fragments, pre-scaled by CC.
  bf16x8 qreg[2][4];
#pragma unroll
  for (int u = 0; u < 2; ++u) {
    int qr = (u == 0 ? qrow0A : qrow0B);
#pragma unroll
    for (int ks = 0; ks < 4; ++ks) {
      bf16x8 v = *(const bf16x8*)(QKV +
          (int64_t)(b * 2048 + qr + wr0 + l16) * 3072 + h * 128 + ks * 32 +
          quad * 8);
#pragma unroll
      for (int e = 0; e < 8; ++e) v[e] = (bf16)((float)v[e] * CC);
      qreg[u][ks] = v;
    }
  }

  f32x4 oacc[2][8] = {};
  float mrow[2] = {-3.0e38f, -3.0e38f};
  float lrow[2] = {0.f, 0.f};

  for (int it = 0; it < niters; ++it) {
    const int cur = it & 1;
    const int n0 = it * 64;
    bf16* sKc = sK[cur];
    bf16* sVc = sV[cur];
    const bool actA = (it <= p);

    asm volatile("s_waitcnt vmcnt(0)\n\ts_barrier" ::: "memory");
    if (it + 1 < niters) stage(n0 + 64, sK[cur ^ 1], sV[cur ^ 1]);

    // ---- S^T = K Q^T : sacc[u][mj], row=kv=mj*16+quad*4+r, col=q=l16 ----
    f32x4 sacc[2][4] = {};
    if (actA) {
#pragma unroll
      for (int ks = 0; ks < 4; ++ks) {
        bf16x8 ak[4];
#pragma unroll
        for (int mj = 0; mj < 4; ++mj) {
          int kvr = mj * 16 + l16;
          int G = ks * 4 + quad;
          int slot = (G & 8) | ((G ^ kvr) & 7);
          ak[mj] = *(const bf16x8*)(sKc + kvr * 128 + slot * 8);
        }
        __builtin_amdgcn_s_setprio(1);
#pragma unroll
        for (int mj = 0; mj < 4; ++mj) {
          sacc[0][mj] = __builtin_amdgcn_mfma_f32_16x16x32_bf16(
              ak[mj], qreg[0][ks], sacc[0][mj], 0, 0, 0);
          sacc[1][mj] = __builtin_amdgcn_mfma_f32_16x16x32_bf16(
              ak[mj], qreg[1][ks], sacc[1][mj], 0, 0, 0);
        }
        __builtin_amdgcn_s_setprio(0);
      }
    } else {
#pragma unroll
      for (int ks = 0; ks < 4; ++ks) {
        bf16x8 ak[4];
#pragma unroll
        for (int mj = 0; mj < 4; ++mj) {
          int kvr = mj * 16 + l16;
          int G = ks * 4 + quad;
          int slot = (G & 8) | ((G ^ kvr) & 7);
          ak[mj] = *(const bf16x8*)(sKc + kvr * 128 + slot * 8);
        }
        __builtin_amdgcn_s_setprio(1);
#pragma unroll
        for (int mj = 0; mj < 4; ++mj)
          sacc[1][mj] = __builtin_amdgcn_mfma_f32_16x16x32_bf16(
              ak[mj], qreg[1][ks], sacc[1][mj], 0, 0, 0);
        __builtin_amdgcn_s_setprio(0);
      }
    }

    // ---- online softmax (log2 domain; CC already folded) -> pb in regs ----
    short4_t pb[2][4];
    auto softmax_u = [&](int u, bool last, int qrow0u) {
      if (last) {
        int qg = qrow0u + wr0 + l16;
#pragma unroll
        for (int mj = 0; mj < 4; ++mj)
#pragma unroll
          for (int r = 0; r < 4; ++r) {
            int kv = n0 + mj * 16 + quad * 4 + r;
            if (kv > qg) sacc[u][mj][r] = -3.0e38f;
          }
      }
      f32x4 m01, m23;
#pragma unroll
      for (int r = 0; r < 4; ++r) {
        m01[r] = fmaxf(sacc[u][0][r], sacc[u][1][r]);
        m23[r] = fmaxf(sacc[u][2][r], sacc[u][3][r]);
      }
      float mx = fmaxf(fmaxf(fmaxf(m01[0], m01[1]), fmaxf(m01[2], m01[3])),
                       fmaxf(fmaxf(m23[0], m23[1]), fmaxf(m23[2], m23[3])));
      mx = fmaxf(mx, __shfl_xor(mx, 16));
      mx = fmaxf(mx, __shfl_xor(mx, 32));
      if (!__all(mx <= mrow[u] + 11.0f)) {  // T13 defer-rescale
        float mnew = fmaxf(mrow[u], mx);
        float alpha = fast_exp2(mrow[u] - mnew);
        lrow[u] *= alpha;
#pragma unroll
        for (int dj = 0; dj < 8; ++dj)
#pragma unroll
          for (int r = 0; r < 4; ++r) oacc[u][dj][r] *= alpha;
        mrow[u] = mnew;
      }
      float rs = 0.f;
#pragma unroll
      for (int mj = 0; mj < 4; ++mj) {
        bf16x4 p4;
#pragma unroll
        for (int r = 0; r < 4; ++r) {
          float pv = fast_exp2(sacc[u][mj][r] - mrow[u]);
          rs += pv;
          p4[r] = (bf16)pv;
        }
        pb[u][mj] = __builtin_bit_cast(short4_t, p4);
      }
      rs += __shfl_xor(rs, 16);
      rs += __shfl_xor(rs, 32);
      lrow[u] += rs;
    };
    if (actA) softmax_u(0, it == p, qrow0A);
    softmax_u(1, it == niters - 1, qrow0B);

    // ---- O^T += V^T P^T via 16x16x16 (P in registers, no sP) ----
#pragma unroll
    for (int mj = 0; mj < 4; ++mj) {
      const int sbase = mj * 2 + (quad >> 1);
      const int soff = (quad & 1) * 4;
      short4_t av[8];
#pragma unroll
      for (int dj = 0; dj < 8; ++dj) {
        int d = dj * 16 + l16;
        av[dj] = *(const short4_t*)(sVc + d * 64 + ((sbase ^ (d & 7)) * 8) + soff);
      }
      __builtin_amdgcn_s_setprio(1);
      if (actA) {
#pragma unroll
        for (int dj = 0; dj < 8; ++dj) {
          oacc[0][dj] = __builtin_amdgcn_mfma_f32_16x16x16bf16_1k(
              av[dj], pb[0][mj], oacc[0][dj], 0, 0, 0);
          oacc[1][dj] = __builtin_amdgcn_mfma_f32_16x16x16bf16_1k(
              av[dj], pb[1][mj], oacc[1][dj], 0, 0, 0);
        }
      } else {
#pragma unroll
        for (int dj = 0; dj < 8; ++dj)
          oacc[1][dj] = __builtin_amdgcn_mfma_f32_16x16x16bf16_1k(
              av[dj], pb[1][mj], oacc[1][dj], 0, 0, 0);
      }
      __builtin_amdgcn_s_setprio(0);
    }
  }

  // ---- epilogue ----
#pragma unroll
  for (int u = 0; u < 2; ++u) {
    int qrow0u = (u == 0 ? qrow0A : qrow0B);
    float inv = 1.0f / lrow[u];
    int64_t grow = b * 2048 + qrow0u + wr0 + l16;
#pragma unroll
    for (int dj = 0; dj < 8; ++dj) {
      bf16x4 o4;
#pragma unroll
      for (int r = 0; r < 4; ++r) o4[r] = (bf16)(oacc[u][dj][r] * inv);
      *(bf16x4*)(Out + grow * 2048 + h * 128 + dj * 16 + quad * 4) = o4;
    }
  }
}

// ---------------------------------------------------------------------------
// Fused prep: convert_x (blocks 0..8191), transpose Wq/Wk/Wv/Wo (64x64 tiles),
// concat bias (last 12 blocks). One launch instead of six.
// ---------------------------------------------------------------------------
__device__ __forceinline__ void tr_tile(const float* __restrict__ W,
                                        bf16* __restrict__ Wt, int K, int N,
                                        int bx, int by, int t, float* tile) {
  int tx = t & 63, ty = t >> 6;
#pragma unroll
  for (int q2 = 0; q2 < 16; ++q2) {
    int r = ty + q2 * 4;
    tile[r * 65 + tx] = W[(int64_t)(by * 64 + r) * N + bx * 64 + tx];
  }
  __syncthreads();
#pragma unroll
  for (int q2 = 0; q2 < 16; ++q2) {
    int n = ty + q2 * 4;
    Wt[(int64_t)(bx * 64 + n) * K + by * 64 + tx] = (bf16)tile[tx * 65 + n];
  }
}

__global__ __launch_bounds__(256) void prep(
    const float* __restrict__ x, const float* __restrict__ Wq,
    const float* __restrict__ Wk, const float* __restrict__ Wv,
    const float* __restrict__ Wo, const float* __restrict__ bq,
    const float* __restrict__ bk, const float* __restrict__ bv,
    bf16* __restrict__ xb, bf16* __restrict__ wqkvT, bf16* __restrict__ woT,
    float* __restrict__ bqkv) {
  __shared__ float tile[64 * 65];
  const int bid = blockIdx.x;
  const int t = threadIdx.x;
  if (bid < 8192) {  // convert x -> bf16
    int idx = bid * 256 + t;
    float4 v = ((const float4*)x)[idx];
    bf16x4 o = {(bf16)v.x, (bf16)v.y, (bf16)v.z, (bf16)v.w};
    ((bf16x4*)xb)[idx] = o;
  } else if (bid < 8192 + 1024) {  // Wq
    int b2 = bid - 8192;
    tr_tile(Wq, wqkvT, 2048, 2048, b2 & 31, b2 >> 5, t, tile);
  } else if (bid < 8192 + 1024 + 256) {  // Wk
    int b2 = bid - (8192 + 1024);
    tr_tile(Wk, wqkvT + 2048 * 2048, 2048, 512, b2 & 7, b2 >> 3, t, tile);
  } else if (bid < 8192 + 1024 + 512) {  // Wv
    int b2 = bid - (8192 + 1024 + 256);
    tr_tile(Wv, wqkvT + 2560 * 2048, 2048, 512, b2 & 7, b2 >> 3, t, tile);
  } else if (bid < 8192 + 1024 + 512 + 1024) {  // Wo
    int b2 = bid - (8192 + 1024 + 512);
    tr_tile(Wo, woT, 2048, 2048, b2 & 31, b2 >> 5, t, tile);
  } else {  // bias concat (12 blocks)
    int i = (bid - (8192 + 1024 + 512 + 1024)) * 256 + t;
    if (i < 3072)
      bqkv[i] = i < 2048 ? bq[i] : (i < 2560 ? bk[i - 2048] : bv[i - 2560]);
  }
}

// ---------------------------------------------------------------------------
extern "C" void kernel_launch(void* const* d_in, const int* in_sizes, int n_in,
                              void* d_out, int out_size, void* d_ws,
                              size_t ws_size, hipStream_t stream) {
  const float* x = (const float*)d_in[0];
  const float* Wq = (const float*)d_in[1];
  const float* bq = (const float*)d_in[2];
  const float* Wk = (const float*)d_in[3];
  const float* bk = (const float*)d_in[4];
  const float* Wv = (const float*)d_in[5];
  const float* bv = (const float*)d_in[6];
  const float* Wo = (const float*)d_in[7];
  const float* bo = (const float*)d_in[8];
  float* out = (float*)d_out;

  char* ws = (char*)d_ws;
  bf16* xb = (bf16*)(ws);
  bf16* wqkvT = (bf16*)(ws + 16777216);
  bf16* woT = (bf16*)(ws + 29360128);
  float* bqkv = (float*)(ws + 37748736);
  bf16* qkv = (bf16*)(ws + 37761024);
  bf16* vt = (bf16*)(ws + 62926848);
  bf16* attnb = (bf16*)(ws + 67121152);

  prep<<<8192 + 1024 + 512 + 1024 + 12, 256, 0, stream>>>(
      x, Wq, Wk, Wv, Wo, bq, bk, bv, xb, wqkvT, woT, bqkv);

  // QKV = xb @ WqkvT^T + bqkv [4096 x 3072]; V columns go transposed to vt.
  gemm_bt<false, true><<<dim3(24, 32), 256, 0, stream>>>(
      xb, wqkvT, bqkv, qkv, 4096, 3072, 2048, vt);
  attn<<<dim3(16, 16, 2), 256, 0, stream>>>(qkv, vt, attnb);
  // out = attnb @ WoT^T + bo    [4096 x 2048] fp32
  gemm_bt<true, false><<<dim3(16, 32), 256, 0, stream>>>(
      attnb, woT, bo, out, 4096, 2048, 2048, nullptr);
}